// Round 17
// baseline (89.419 us; speedup 1.0000x reference)
//
#include <hip/hip_runtime.h>

#define IC 128
#define OC 256
#define RR 64
#define CCOLS 64
#define HO 62
#define WO 62
#define NB 16

// ws layout:
//   T    : x-major bf16 image  T[b][y][ck16][x 64][8c] = 16 MB (+256 pad)
//   W9Tf : fragment-major bf16 weights (R8 layout), 589824 B
//   bias : 256 floats
#define T_BYTES (NB * 64 * 16 * 64 * 16)        // 16777216
#define T_PAD   256
#define W9T_BYTES (9 * OC * IC * 2)             // 589824
#define CHUNK_STRIDE 8192                       // 8 ocgroups * 64 lanes * 16 B

typedef __bf16 bf16x8 __attribute__((ext_vector_type(8)));
typedef float f32x16 __attribute__((ext_vector_type(16)));

__device__ __forceinline__ unsigned short f2bf(float f) {
    unsigned u = __builtin_bit_cast(unsigned, f);
    u += 0x7FFFu + ((u >> 16) & 1u);   // round-to-nearest-even
    return (unsigned short)(u >> 16);
}

// Transpose images [b][c][y][x] fp32 -> T[b][y][ck16][x][8c] bf16.
__global__ void transpose_img(const float* __restrict__ images,
                              unsigned char* __restrict__ T) {
    const int y = blockIdx.x;
    const int b = blockIdx.y;
    const int xs = threadIdx.x & 63;
    const int ckq = threadIdx.x >> 6;           // 0..3
    const float* __restrict__ imgb = images + (size_t)b * (IC * RR * CCOLS);
    unsigned char* __restrict__ trow = T + (((size_t)b * 64 + y) * 16) * 1024;
    #pragma unroll
    for (int h = 0; h < 4; ++h) {
        const int ck = ckq + 4 * h;             // 0..15
        const int c0 = ck * 8;
        const float* __restrict__ p = imgb + (size_t)c0 * (RR * CCOLS) + y * CCOLS + xs;
        unsigned v0, v1, v2, v3;
        v0 = (unsigned)f2bf(p[0])              | ((unsigned)f2bf(p[RR * CCOLS])     << 16);
        v1 = (unsigned)f2bf(p[2 * RR * CCOLS]) | ((unsigned)f2bf(p[3 * RR * CCOLS]) << 16);
        v2 = (unsigned)f2bf(p[4 * RR * CCOLS]) | ((unsigned)f2bf(p[5 * RR * CCOLS]) << 16);
        v3 = (unsigned)f2bf(p[6 * RR * CCOLS]) | ((unsigned)f2bf(p[7 * RR * CCOLS]) << 16);
        *(uint4*)(trow + ck * 1024 + xs * 16) = make_uint4(v0, v1, v2, v3);
    }
}

// prep: blocks 0..OC-1 scatter weights; block OC densifies the bias.
__global__ void prep_weights(const float* __restrict__ wv,
                             const int* __restrict__ iwi,
                             const int* __restrict__ flen,
                             const int* __restrict__ sp,
                             unsigned char* __restrict__ W9Tf,
                             const int* __restrict__ bias_index,
                             const float* __restrict__ bias_value,
                             float* __restrict__ bias_dense, int nbias) {
    if (blockIdx.x == OC) {
        int t = threadIdx.x;
        if (t < OC) bias_dense[t] = 0.f;
        __syncthreads();
        if (t < nbias) atomicAdd(&bias_dense[bias_index[t]], bias_value[t]);
        return;
    }
    const int oc = blockIdx.x;
    const int s = sp[oc];
    const int n = flen[oc];
    const int g = oc >> 5;
    for (int t = threadIdx.x; t < n; t += blockDim.x) {
        const int ix = iwi[s + t];          // c*4096 + ky*64 + kx
        const int c = ix >> 12;
        const int rem = ix & 4095;
        const int ky = rem >> 6, kx = rem & 63;
        const int kp = ky * 3 + kx;
        const int ck = c >> 4;
        const int khalf = (c >> 3) & 1;
        const int lane = (oc & 31) + (khalf << 5);
        const size_t off = (size_t)(kp * 8 + ck) * CHUNK_STRIDE +
                           g * 1024 + lane * 16 + (c & 7) * 2;
        *(unsigned short*)(W9Tf + off) = f2bf(wv[s + t]);
    }
}

// LDS-free, TLP-max conv. Block = (b, y, oc-half of 128) = 256 threads =
// 4 waves; wave w: ONE oc-group (32 oc) x 64 x (2 n-tiles). Per K-chunk:
// 1 A-load + 2 B-loads + 2 MFMAs; acc = 32 AGPR (half of R16) so unified
// regs ~100 -> 5 waves/SIMD tier; grid 1984 blocks = 7.75 blocks/CU so
// packing fills the machine (R16: grid 992 capped TLP at 10.4 waves/CU,
// all pipes <25% = latency-bound; resident waves is the only lever that
// has ever moved this op). 4 waves/block read identical B -> L1 dedup.
__global__ __launch_bounds__(256, 4) void conv_mfma(
    const unsigned char* __restrict__ T,
    const unsigned char* __restrict__ W9Tf,
    const float* __restrict__ bias_dense,
    float* __restrict__ out)
{
    const int y = blockIdx.x;
    const int b = blockIdx.y;
    const int och = blockIdx.z;       // 0..1
    const int t = threadIdx.x;
    const int w = t >> 6;             // 0..3
    const int l = t & 63;
    const int lm = l & 31;            // m-row / n-col within frag
    const int lhi = l >> 5;           // k-half

    const int ocg = och * 4 + w;      // this wave's oc-group (0..7)

    // lane's coalesced A base for its oc-group
    const unsigned char* __restrict__ pA = W9Tf + ocg * 1024 + l * 16;
    // lane's B base: row (b,y), k-half lhi, column lm
    const unsigned char* __restrict__ pB =
        T + (((size_t)b * 64 + y) * 16 + lhi) * 1024 + lm * 16;

    // B reader for chunk idx (compile-time ky/kx/ci under full unroll):
    // addr = pB + ky*16384 + ci*2048 + kx*16 + n*512  (x-overrun lanes read
    // the next ck row / tail pad; their outputs are never stored).
    auto readB = [&](int idx, bf16x8& b0, bf16x8& b1) {
        const int kp = idx >> 3, ci = idx & 7;
        const int ky = kp / 3, kx = kp % 3;
        const unsigned char* __restrict__ p = pB + ky * 16384 + ci * 2048 + kx * 16;
        b0 = *(const bf16x8*)(p);
        b1 = *(const bf16x8*)(p + 512);
    };

    // prologue: prefetch A chunks 0..2, B chunks 0..1
    bf16x8 aC  = *(const bf16x8*)(pA);
    bf16x8 aN1 = *(const bf16x8*)(pA + CHUNK_STRIDE);
    bf16x8 aN2 = *(const bf16x8*)(pA + 2 * CHUNK_STRIDE);
    bf16x8 b0C, b1C, b0N1, b1N1;
    readB(0, b0C, b1C);
    readB(1, b0N1, b1N1);

    f32x16 c0 = {}, c1 = {};

    #pragma unroll
    for (int idx = 0; idx < 72; ++idx) {
        bf16x8 aN3, b0N2, b1N2;
        if (idx + 3 < 72)
            aN3 = *(const bf16x8*)(pA + (size_t)(idx + 3) * CHUNK_STRIDE);
        if (idx + 2 < 72) readB(idx + 2, b0N2, b1N2);

        c0 = __builtin_amdgcn_mfma_f32_32x32x16_bf16(aC, b0C, c0, 0, 0, 0);
        c1 = __builtin_amdgcn_mfma_f32_32x32x16_bf16(aC, b1C, c1, 0, 0, 0);

        aC = aN1; aN1 = aN2;                     // SSA-renamed, no copies
        if (idx + 3 < 72) aN2 = aN3;
        b0C = b0N1; b1C = b1N1;
        if (idx + 2 < 72) { b0N1 = b0N2; b1N1 = b1N2; }
    }

    // ---- epilogue: bias + store ----
    // C/D 32x32: col = lane&31, row = (reg&3) + 8*(reg>>2) + 4*(lane>>5)
    const int ocw = ocg * 32;
    #pragma unroll
    for (int r = 0; r < 16; ++r) {
        const int oc = ocw + (r & 3) + 8 * (r >> 2) + 4 * lhi;
        const float bv = bias_dense[oc];
        const size_t ob = (((size_t)b * OC + oc) * HO + y) * WO;
        out[ob + lm] = c0[r] + bv;               // x = lm < 62 always
        if (lm < 30)
            out[ob + 32 + lm] = c1[r] + bv;      // x = 32+lm, clip at 62
    }
}

extern "C" void kernel_launch(void* const* d_in, const int* in_sizes, int n_in,
                              void* d_out, int out_size, void* d_ws, size_t ws_size,
                              hipStream_t stream) {
    const float* images             = (const float*)d_in[0];
    const float* weight_value       = (const float*)d_in[1];
    const int*   image_weight_index = (const int*)d_in[2];
    const int*   filter_lengths     = (const int*)d_in[3];
    const int*   start_points       = (const int*)d_in[4];
    const int*   bias_index         = (const int*)d_in[5];
    const float* bias_value         = (const float*)d_in[6];
    float* out = (float*)d_out;

    unsigned char* T    = (unsigned char*)d_ws;
    unsigned char* W9Tf = (unsigned char*)d_ws + T_BYTES + T_PAD;
    float* bias_dense   = (float*)(W9Tf + W9T_BYTES);

    hipMemsetAsync(W9Tf, 0, W9T_BYTES, stream);
    transpose_img<<<dim3(64, NB), 256, 0, stream>>>(images, T);
    prep_weights<<<OC + 1, 256, 0, stream>>>(weight_value, image_weight_index,
                                             filter_lengths, start_points, W9Tf,
                                             bias_index, bias_value, bias_dense,
                                             in_sizes[5]);

    dim3 grid(HO, NB, 2);
    conv_mfma<<<grid, 256, 0, stream>>>(T, W9Tf, bias_dense, out);
}

// Round 18
// 75.264 us; speedup vs baseline: 1.1881x; 1.1881x over previous
//
#include <hip/hip_runtime.h>
#include <stdint.h>

#define IC 128
#define OC 256
#define RR 64
#define CCOLS 64
#define HO 62
#define WO 62
#define NB 16

// Fragment-major dense bf16 weights: W9Tf[chunk][g][lane][16B],
// chunk = kp*8+ck (72), g = oc>>5 (8), lane = (oc&31)+32*khalf.
// One K-step (BK=32) = 2 chunks = 16 KB contiguous -> global_load_lds-able.
#define W9T_BYTES (9 * OC * IC * 2)   // 589824
#define CHUNK_STRIDE 8192
#define KSTEP_BYTES 16384             // 2 chunks
#define LDSROW 16384                  // one image row: 64 x * 256 B
#define ABUF0 49152                   // A double-buffer slots
#define ABUF1 65536
#define LDS_TOTAL 81920

typedef __bf16 bf16x8 __attribute__((ext_vector_type(8)));
typedef float f32x16 __attribute__((ext_vector_type(16)));

__device__ __forceinline__ unsigned short f2bf(float f) {
    unsigned u = __builtin_bit_cast(unsigned, f);
    u += 0x7FFFu + ((u >> 16) & 1u);   // round-to-nearest-even
    return (unsigned short)(u >> 16);
}

// async global->LDS 16B copy: LDS dest = (wave-uniform base) + lane*16,
// global src = per-lane. AS casts via uintptr_t round-trip (CK idiom).
__device__ __forceinline__ void gload_lds16(const void* g, void* l) {
    __builtin_amdgcn_global_load_lds(
        (const __attribute__((address_space(1))) unsigned int*)(uintptr_t)g,
        (__attribute__((address_space(3))) unsigned int*)(uintptr_t)l,
        16, 0, 0);
}

// prep: blocks 0..OC-1 scatter weights; block OC densifies the bias.
__global__ void prep_weights(const float* __restrict__ wv,
                             const int* __restrict__ iwi,
                             const int* __restrict__ flen,
                             const int* __restrict__ sp,
                             unsigned char* __restrict__ W9Tf,
                             const int* __restrict__ bias_index,
                             const float* __restrict__ bias_value,
                             float* __restrict__ bias_dense, int nbias) {
    if (blockIdx.x == OC) {
        int t = threadIdx.x;
        if (t < OC) bias_dense[t] = 0.f;
        __syncthreads();
        if (t < nbias) atomicAdd(&bias_dense[bias_index[t]], bias_value[t]);
        return;
    }
    const int oc = blockIdx.x;
    const int s = sp[oc];
    const int n = flen[oc];
    const int g = oc >> 5;
    for (int t = threadIdx.x; t < n; t += blockDim.x) {
        const int ix = iwi[s + t];          // c*4096 + ky*64 + kx
        const int c = ix >> 12;
        const int rem = ix & 4095;
        const int ky = rem >> 6, kx = rem & 63;
        const int kp = ky * 3 + kx;
        const int ck = c >> 4;
        const int khalf = (c >> 3) & 1;
        const int lane = (oc & 31) + (khalf << 5);
        const size_t off = (size_t)(kp * 8 + ck) * CHUNK_STRIDE +
                           g * 1024 + lane * 16 + (c & 7) * 2;
        *(unsigned short*)(W9Tf + off) = f2bf(wv[s + t]);
    }
}

// m97-style 2-phase K-loop. Block = (b,y) x 256 oc, 256 threads = 4 waves.
// Wave w: oc-groups {2w,2w+1} (2 m-frags) x 64 x (2 n-frags); per K-step
// (BK=32): 8 ds_read_b128 -> 8 MFMAs (32.8 KFLOP/read). B panel (3 rows,
// 48 KB) staged ONCE (K-resident). A panels (16 KB/step) double-buffered
// via global_load_lds — async DMA uses NO VGPRs, so the compiler cannot
// compress the pipeline (the R8-R17 serializer). One barrier drain/step.
__global__ __launch_bounds__(256, 1) void conv_mfma(
    const float* __restrict__ images,
    const unsigned char* __restrict__ W9Tf,
    const float* __restrict__ bias_dense,
    float* __restrict__ out)
{
    const int y = blockIdx.x;
    const int b = blockIdx.y;
    const int t = threadIdx.x;
    const int w = t >> 6;             // 0..3
    const int l = t & 63;
    const int lm = l & 31;            // m-row / n-col within frag
    const int lhi16 = (l >> 5) * 16;  // k-half byte offset

    __shared__ unsigned char lds[LDS_TOTAL];   // 48K B-panel + 2x16K A-dbuf

    const float* __restrict__ imgb = images + (size_t)b * (IC * RR * CCOLS);

    // ---- issue A-panel step 0 into ABUF0 (async, no regs) ----
    #pragma unroll
    for (int i = 0; i < 4; ++i)
        gload_lds16(W9Tf + (i * 4 + w) * 1024 + (size_t)l * 16,
                    lds + ABUF0 + (i * 4 + w) * 1024);

    // ---- stage B: 3 image rows, fp32 -> bf16, [x][c], XOR-swizzled ----
    {
        const int xs = t & 63;
        const int og = t >> 6;              // 0..3
        const int swz = (xs & 7) << 4;
        #pragma unroll
        for (int krow = 0; krow < 3; ++krow) {
            #pragma unroll
            for (int h = 0; h < 4; ++h) {
                const int c0 = (og + 4 * h) * 8;    // octet base channel
                const float* __restrict__ p =
                    imgb + (size_t)c0 * (RR * CCOLS) + (y + krow) * CCOLS + xs;
                unsigned v0, v1, v2, v3;
                v0 = (unsigned)f2bf(p[0])              | ((unsigned)f2bf(p[RR * CCOLS])     << 16);
                v1 = (unsigned)f2bf(p[2 * RR * CCOLS]) | ((unsigned)f2bf(p[3 * RR * CCOLS]) << 16);
                v2 = (unsigned)f2bf(p[4 * RR * CCOLS]) | ((unsigned)f2bf(p[5 * RR * CCOLS]) << 16);
                v3 = (unsigned)f2bf(p[6 * RR * CCOLS]) | ((unsigned)f2bf(p[7 * RR * CCOLS]) << 16);
                *(uint4*)(lds + krow * LDSROW + xs * 256 + ((c0 * 2) ^ swz)) =
                    make_uint4(v0, v1, v2, v3);
            }
        }
    }

    __syncthreads();   // B complete + A step 0 complete (vmcnt drain)

    // named accumulators c<m><n> (static indexing -> no scratch)
    f32x16 c00 = {}, c01 = {}, c10 = {}, c11 = {};

    #pragma unroll
    for (int s = 0; s < 36; ++s) {
        const int abase = (s & 1) ? ABUF1 : ABUF0;
        const int nbase = (s & 1) ? ABUF0 : ABUF1;
        // issue next A-panel (fire-and-forget DMA, in flight during MFMAs)
        if (s + 1 < 36) {
            #pragma unroll
            for (int i = 0; i < 4; ++i)
                gload_lds16(W9Tf + (size_t)(s + 1) * KSTEP_BYTES +
                                (i * 4 + w) * 1024 + (size_t)l * 16,
                            lds + nbase + (i * 4 + w) * 1024);
        }
        // compute current K-step: 2 chunks x (2m x 2n) MFMAs
        #pragma unroll
        for (int ch = 0; ch < 2; ++ch) {
            const int idx = 2 * s + ch;              // compile-time chunk id
            const int kp = idx >> 3, ck = idx & 7;
            const int ky = kp / 3, kx = kp % 3;
            const bf16x8 a0 = *(const bf16x8*)(
                lds + abase + ch * CHUNK_STRIDE + (2 * w + 0) * 1024 + l * 16);
            const bf16x8 a1 = *(const bf16x8*)(
                lds + abase + ch * CHUNK_STRIDE + (2 * w + 1) * 1024 + l * 16);
            const int x0 = lm + kx;                  // <= 33, in-bounds
            int x1 = 32 + lm + kx;
            x1 = x1 > 63 ? 63 : x1;   // pad lanes: dup col 63 (discarded)
            const unsigned char* __restrict__ row = lds + ky * LDSROW;
            const int pb0 = (x0 * 256 + (lhi16 ^ ((x0 & 7) << 4))) ^ (ck * 32);
            const int pb1 = (x1 * 256 + (lhi16 ^ ((x1 & 7) << 4))) ^ (ck * 32);
            const bf16x8 b0 = *(const bf16x8*)(row + pb0);
            const bf16x8 b1 = *(const bf16x8*)(row + pb1);
            c00 = __builtin_amdgcn_mfma_f32_32x32x16_bf16(a0, b0, c00, 0, 0, 0);
            c10 = __builtin_amdgcn_mfma_f32_32x32x16_bf16(a1, b0, c10, 0, 0, 0);
            c01 = __builtin_amdgcn_mfma_f32_32x32x16_bf16(a0, b1, c01, 0, 0, 0);
            c11 = __builtin_amdgcn_mfma_f32_32x32x16_bf16(a1, b1, c11, 0, 0, 0);
        }
        // drain this step's DMA + sync before buffer flip (T3-minimum)
        __syncthreads();
    }

    // ---- epilogue: bias + store ----
    // C/D 32x32: col = lane&31, row = (reg&3) + 8*(reg>>2) + 4*(lane>>5)
    #pragma unroll
    for (int m = 0; m < 2; ++m) {
        const int ocw = (2 * w + m) * 32;
        const f32x16 d0 = m ? c10 : c00;
        const f32x16 d1 = m ? c11 : c01;
        #pragma unroll
        for (int r = 0; r < 16; ++r) {
            const int oc = ocw + (r & 3) + 8 * (r >> 2) + (lhi16 >> 2);
            const float bv = bias_dense[oc];
            const size_t ob = (((size_t)b * OC + oc) * HO + y) * WO;
            out[ob + lm] = d0[r] + bv;               // x = lm < 62 always
            if (lm < 30)
                out[ob + 32 + lm] = d1[r] + bv;      // x = 32+lm, clip at 62
        }
    }
}

extern "C" void kernel_launch(void* const* d_in, const int* in_sizes, int n_in,
                              void* d_out, int out_size, void* d_ws, size_t ws_size,
                              hipStream_t stream) {
    const float* images             = (const float*)d_in[0];
    const float* weight_value       = (const float*)d_in[1];
    const int*   image_weight_index = (const int*)d_in[2];
    const int*   filter_lengths     = (const int*)d_in[3];
    const int*   start_points       = (const int*)d_in[4];
    const int*   bias_index         = (const int*)d_in[5];
    const float* bias_value         = (const float*)d_in[6];
    float* out = (float*)d_out;

    unsigned char* W9Tf = (unsigned char*)d_ws;
    float* bias_dense = (float*)((char*)d_ws + W9T_BYTES);

    hipMemsetAsync(d_ws, 0, W9T_BYTES, stream);
    prep_weights<<<OC + 1, 256, 0, stream>>>(weight_value, image_weight_index,
                                             filter_lengths, start_points, W9Tf,
                                             bias_index, bias_value, bias_dense,
                                             in_sizes[5]);

    dim3 grid(HO, NB);
    conv_mfma<<<grid, 256, 0, stream>>>(images, W9Tf, bias_dense, out);
}

// Round 19
// 64.997 us; speedup vs baseline: 1.3757x; 1.1580x over previous
//
#include <hip/hip_runtime.h>
#include <stdint.h>

#define IC 128
#define OC 256
#define RR 64
#define CCOLS 64
#define HO 62
#define WO 62
#define NB 16

// Fragment-major dense bf16 weights: W9Tf[chunk][g][lane][16B],
// chunk = kp*8+ck (72), g = oc>>5 (8), lane = (oc&31)+32*khalf.
#define W9T_BYTES (9 * OC * IC * 2)   // 589824
#define CHUNK_STRIDE 8192
// B LDS layout: [krow 3][octet 16][x 64][16B] -> 48 KB, + 1 KB tail pad so
// unclamped x1 (<=65) reads stay in-bounds (garbage lands only in output
// columns >=62 which are never stored).
#define LDS_TOTAL (49152 + 1024)

typedef __bf16 bf16x8 __attribute__((ext_vector_type(8)));
typedef float f32x16 __attribute__((ext_vector_type(16)));

__device__ __forceinline__ unsigned short f2bf(float f) {
    unsigned u = __builtin_bit_cast(unsigned, f);
    u += 0x7FFFu + ((u >> 16) & 1u);   // round-to-nearest-even
    return (unsigned short)(u >> 16);
}

// prep: blocks 0..OC-1 scatter weights; block OC densifies the bias.
__global__ void prep_weights(const float* __restrict__ wv,
                             const int* __restrict__ iwi,
                             const int* __restrict__ flen,
                             const int* __restrict__ sp,
                             unsigned char* __restrict__ W9Tf,
                             const int* __restrict__ bias_index,
                             const float* __restrict__ bias_value,
                             float* __restrict__ bias_dense, int nbias) {
    if (blockIdx.x == OC) {
        int t = threadIdx.x;
        if (t < OC) bias_dense[t] = 0.f;
        __syncthreads();
        if (t < nbias) atomicAdd(&bias_dense[bias_index[t]], bias_value[t]);
        return;
    }
    const int oc = blockIdx.x;
    const int s = sp[oc];
    const int n = flen[oc];
    const int g = oc >> 5;
    for (int t = threadIdx.x; t < n; t += blockDim.x) {
        const int ix = iwi[s + t];          // c*4096 + ky*64 + kx
        const int c = ix >> 12;
        const int rem = ix & 4095;
        const int ky = rem >> 6, kx = rem & 63;
        const int kp = ky * 3 + kx;
        const int ck = c >> 4;
        const int khalf = (c >> 3) & 1;
        const int lane = (oc & 31) + (khalf << 5);
        const size_t off = (size_t)(kp * 8 + ck) * CHUNK_STRIDE +
                           g * 1024 + lane * 16 + (c & 7) * 2;
        *(unsigned short*)(W9Tf + off) = f2bf(wv[s + t]);
    }
}

// One K-chunk step. AV = this step's A-fragment register (loaded 4 steps
// ago by opaque asm). VN = vmcnt literal. All B offsets compile-time.
#define KSTEP1(IDX, AV, VN)                                                   \
  {                                                                           \
    constexpr int kp_ = (IDX) >> 3, ck_ = (IDX) & 7;                          \
    constexpr int ky_ = kp_ / 3, kx_ = kp_ % 3;                               \
    constexpr int off0_ = ky_ * 16384 + ck_ * 2048 + kx_ * 16;                \
    asm volatile("s_waitcnt vmcnt(" VN ")" : "+v"(AV));                       \
    const bf16x8 b0_ = *(const bf16x8*)(pB + off0_);                          \
    const bf16x8 b1_ = *(const bf16x8*)(pB + off0_ + 512);                    \
    acc0 = __builtin_amdgcn_mfma_f32_32x32x16_bf16(AV, b0_, acc0, 0, 0, 0);   \
    acc1 = __builtin_amdgcn_mfma_f32_32x32x16_bf16(AV, b1_, acc1, 0, 0, 0);   \
    if constexpr ((IDX) + 4 < 72)                                             \
      asm volatile("global_load_dwordx4 %0, %1, off"                          \
                   : "=v"(AV)                                                 \
                   : "v"(pA + (size_t)((IDX) + 4) * CHUNK_STRIDE));           \
  }

#define K4(I) KSTEP1((I)+0, aS0, "3") KSTEP1((I)+1, aS1, "3") \
              KSTEP1((I)+2, aS2, "3") KSTEP1((I)+3, aS3, "3")

// Block = one output row (b, y) x all 256 oc. 512 threads = 8 waves.
// Wave w: 32 oc (one 32x32 m-frag) x 64 x (2 n-tiles). R8 champion base +
// (1) conflict-free B layout [krow][octet][x][16B]: wave B-reads/writes are
//     contiguous slot-runs like the A-reads (which measure 0 conflicts);
//     ds_read offsets fold to immediates off one base VGPR.
// (2) asm-opaque A loads + counted s_waitcnt vmcnt(3..0): compiler cannot
//     compress the 4-deep pipeline (the R8-R17 serializer); ordering via
//     "+v" data-dependency (no sched_barrier -> B scheduling stays free).
__global__ __launch_bounds__(512, 2) void conv_mfma(
    const float* __restrict__ images,
    const unsigned char* __restrict__ W9Tf,
    const float* __restrict__ bias_dense,
    float* __restrict__ out)
{
    const int y = blockIdx.x;
    const int b = blockIdx.y;
    const int t = threadIdx.x;
    const int w = t >> 6;
    const int l = t & 63;
    const int lm = l & 31;            // m-row / n-col within frag
    const int lhi = l >> 5;           // k-half

    __shared__ unsigned char lds[LDS_TOTAL];

    const float* __restrict__ imgb = images + (size_t)b * (IC * RR * CCOLS);

    // ---- stage B: 3 rows -> [krow][octet][x][16B] (conflict-free) ----
    {
        const int xs = t & 63;
        const int oct = t >> 6;             // wave-uniform octet base
        #pragma unroll
        for (int krow = 0; krow < 3; ++krow) {
            #pragma unroll
            for (int h = 0; h < 2; ++h) {
                const int o = oct + 8 * h;          // octet 0..15
                const int c0 = o * 8;
                const float* __restrict__ p =
                    imgb + (size_t)c0 * (RR * CCOLS) + (y + krow) * CCOLS + xs;
                unsigned v0, v1, v2, v3;
                v0 = (unsigned)f2bf(p[0])              | ((unsigned)f2bf(p[RR * CCOLS])     << 16);
                v1 = (unsigned)f2bf(p[2 * RR * CCOLS]) | ((unsigned)f2bf(p[3 * RR * CCOLS]) << 16);
                v2 = (unsigned)f2bf(p[4 * RR * CCOLS]) | ((unsigned)f2bf(p[5 * RR * CCOLS]) << 16);
                v3 = (unsigned)f2bf(p[6 * RR * CCOLS]) | ((unsigned)f2bf(p[7 * RR * CCOLS]) << 16);
                // wave writes 64 consecutive 16B slots = 1 KB contiguous
                *(uint4*)(lds + krow * 16384 + o * 1024 + xs * 16) =
                    make_uint4(v0, v1, v2, v3);
            }
        }
    }

    // lane's coalesced A base and B base
    const unsigned char* __restrict__ pA = W9Tf + w * 1024 + l * 16;
    const unsigned char* __restrict__ pB = lds + lhi * 1024 + lm * 16;

    __syncthreads();   // B staged; vmcnt drained -> loop counts only asm loads

    // prologue: issue A chunks 0..3 (opaque -> stays 4-deep in flight)
    bf16x8 aS0, aS1, aS2, aS3;
    asm volatile("global_load_dwordx4 %0, %1, off" : "=v"(aS0) : "v"(pA));
    asm volatile("global_load_dwordx4 %0, %1, off" : "=v"(aS1) : "v"(pA + CHUNK_STRIDE));
    asm volatile("global_load_dwordx4 %0, %1, off" : "=v"(aS2) : "v"(pA + 2 * CHUNK_STRIDE));
    asm volatile("global_load_dwordx4 %0, %1, off" : "=v"(aS3) : "v"(pA + 3 * CHUNK_STRIDE));

    f32x16 acc0 = {}, acc1 = {};

    // 72 straight-line K-steps, steady-state vmcnt(3), tail 3->0
    K4(0) K4(4) K4(8) K4(12) K4(16) K4(20) K4(24) K4(28) K4(32)
    K4(36) K4(40) K4(44) K4(48) K4(52) K4(56) K4(60) K4(64)
    KSTEP1(68, aS0, "3") KSTEP1(69, aS1, "2")
    KSTEP1(70, aS2, "1") KSTEP1(71, aS3, "0")

    // ---- epilogue: bias + store ----
    // C/D 32x32: col = lane&31, row = (reg&3) + 8*(reg>>2) + 4*(lane>>5)
    const int ocw = 32 * w;
    #pragma unroll
    for (int r = 0; r < 16; ++r) {
        const int oc = ocw + (r & 3) + 8 * (r >> 2) + 4 * lhi;
        const float bv = bias_dense[oc];
        const size_t ob = (((size_t)b * OC + oc) * HO + y) * WO;
        out[ob + lm] = acc0[r] + bv;             // x = lm < 62 always
        if (lm < 30)
            out[ob + 32 + lm] = acc1[r] + bv;    // x = 32+lm, clip at 62
    }
}

extern "C" void kernel_launch(void* const* d_in, const int* in_sizes, int n_in,
                              void* d_out, int out_size, void* d_ws, size_t ws_size,
                              hipStream_t stream) {
    const float* images             = (const float*)d_in[0];
    const float* weight_value       = (const float*)d_in[1];
    const int*   image_weight_index = (const int*)d_in[2];
    const int*   filter_lengths     = (const int*)d_in[3];
    const int*   start_points       = (const int*)d_in[4];
    const int*   bias_index         = (const int*)d_in[5];
    const float* bias_value         = (const float*)d_in[6];
    float* out = (float*)d_out;

    unsigned char* W9Tf = (unsigned char*)d_ws;
    float* bias_dense = (float*)((char*)d_ws + W9T_BYTES);

    hipMemsetAsync(d_ws, 0, W9T_BYTES, stream);
    prep_weights<<<OC + 1, 256, 0, stream>>>(weight_value, image_weight_index,
                                             filter_lengths, start_points, W9Tf,
                                             bias_index, bias_value, bias_dense,
                                             in_sizes[5]);

    dim3 grid(HO, NB);
    conv_mfma<<<grid, 512, 0, stream>>>(images, W9Tf, bias_dense, out);
}

// Round 20
// 64.735 us; speedup vs baseline: 1.3813x; 1.0040x over previous
//
#include <hip/hip_runtime.h>
#include <stdint.h>

#define IC 128
#define OC 256
#define RR 64
#define CCOLS 64
#define HO 62
#define WO 62
#define NB 16

// Fragment-major dense bf16 weights: W9Tf[chunk][g][lane][16B],
// chunk = kp*8+ck (72), g = oc>>5 (8), lane = (oc&31)+32*khalf.
#define W9T_BYTES (9 * OC * IC * 2)   // 589824
#define CHUNK_STRIDE 8192
// B LDS layout: [krow 3][octet 16][x 64][16B] -> 48 KB + 1 KB tail pad
// (unclamped x1 reads land in pad; those output columns are never stored).
#define LDS_TOTAL (49152 + 1024)

typedef __bf16 bf16x8 __attribute__((ext_vector_type(8)));
typedef float f32x16 __attribute__((ext_vector_type(16)));

__device__ __forceinline__ unsigned short f2bf(float f) {
    unsigned u = __builtin_bit_cast(unsigned, f);
    u += 0x7FFFu + ((u >> 16) & 1u);   // round-to-nearest-even
    return (unsigned short)(u >> 16);
}

// prep: blocks 0..OC-1 scatter weights; block OC densifies the bias.
__global__ void prep_weights(const float* __restrict__ wv,
                             const int* __restrict__ iwi,
                             const int* __restrict__ flen,
                             const int* __restrict__ sp,
                             unsigned char* __restrict__ W9Tf,
                             const int* __restrict__ bias_index,
                             const float* __restrict__ bias_value,
                             float* __restrict__ bias_dense, int nbias) {
    if (blockIdx.x == OC) {
        int t = threadIdx.x;
        if (t < OC) bias_dense[t] = 0.f;
        __syncthreads();
        if (t < nbias) atomicAdd(&bias_dense[bias_index[t]], bias_value[t]);
        return;
    }
    const int oc = blockIdx.x;
    const int s = sp[oc];
    const int n = flen[oc];
    const int g = oc >> 5;
    for (int t = threadIdx.x; t < n; t += blockDim.x) {
        const int ix = iwi[s + t];          // c*4096 + ky*64 + kx
        const int c = ix >> 12;
        const int rem = ix & 4095;
        const int ky = rem >> 6, kx = rem & 63;
        const int kp = ky * 3 + kx;
        const int ck = c >> 4;
        const int khalf = (c >> 3) & 1;
        const int lane = (oc & 31) + (khalf << 5);
        const size_t off = (size_t)(kp * 8 + ck) * CHUNK_STRIDE +
                           g * 1024 + lane * 16 + (c & 7) * 2;
        *(unsigned short*)(W9Tf + off) = f2bf(wv[s + t]);
    }
}

// One K-chunk step. AV = A-fragment loaded 4 steps ago (opaque asm).
// b0c/b1c = B-fragments ds_read 1 step ago (opaque asm). VN/LGN = counted
// waits. Per step: issue B(s+1) reads -> wait A(s) arrived + B(s) arrived
// (lgkmcnt(2): only the 2 just-issued reads may remain outstanding) ->
// sched_barrier(0) (rule #18: stops MFMA hoisting past an asm waitcnt) ->
// 2 MFMAs -> issue A(s+4). Both streams now beyond compiler compression.
#define KSTEP1(IDX, AV, VN, LGN)                                              \
  {                                                                           \
    if constexpr ((IDX) + 1 < 72) {                                           \
      constexpr int i1_ = (IDX) + 1;                                          \
      constexpr int kp1_ = i1_ >> 3, ck1_ = i1_ & 7;                          \
      constexpr int o1_ = (kp1_ / 3) * 16384 + ck1_ * 2048 + (kp1_ % 3) * 16; \
      asm volatile("ds_read_b128 %0, %1" : "=v"(b0n) : "v"(bB + o1_));        \
      asm volatile("ds_read_b128 %0, %1" : "=v"(b1n) : "v"(bB + o1_ + 512));  \
    }                                                                         \
    asm volatile("s_waitcnt vmcnt(" VN ") lgkmcnt(" LGN ")" : "+v"(AV));      \
    __builtin_amdgcn_sched_barrier(0);                                        \
    acc0 = __builtin_amdgcn_mfma_f32_32x32x16_bf16(AV, b0c, acc0, 0, 0, 0);   \
    acc1 = __builtin_amdgcn_mfma_f32_32x32x16_bf16(AV, b1c, acc1, 0, 0, 0);   \
    if constexpr ((IDX) + 4 < 72)                                             \
      asm volatile("global_load_dwordx4 %0, %1, off"                          \
                   : "=v"(AV)                                                 \
                   : "v"(pA + (size_t)((IDX) + 4) * CHUNK_STRIDE));           \
    if constexpr ((IDX) + 1 < 72) { b0c = b0n; b1c = b1n; }                   \
  }

#define K4(I) KSTEP1((I)+0, aS0, "3", "2") KSTEP1((I)+1, aS1, "3", "2") \
              KSTEP1((I)+2, aS2, "3", "2") KSTEP1((I)+3, aS3, "3", "2")

// Block = one output row (b, y) x all 256 oc. 512 threads = 8 waves.
// Wave w: 32 oc (one 32x32 m-frag) x 64 x (2 n-tiles). R19 base
// (conflict-free B layout + opaque 4-deep A pipeline) + opaque 1-deep
// B pipeline with counted lgkmcnt — removes the last serial latency
// (~120 cyc LDS round-trip per step, the post-R19 residual).
__global__ __launch_bounds__(512, 2) void conv_mfma(
    const float* __restrict__ images,
    const unsigned char* __restrict__ W9Tf,
    const float* __restrict__ bias_dense,
    float* __restrict__ out)
{
    const int y = blockIdx.x;
    const int b = blockIdx.y;
    const int t = threadIdx.x;
    const int w = t >> 6;
    const int l = t & 63;
    const int lm = l & 31;            // m-row / n-col within frag
    const int lhi = l >> 5;           // k-half

    __shared__ unsigned char lds[LDS_TOTAL];

    const float* __restrict__ imgb = images + (size_t)b * (IC * RR * CCOLS);

    // ---- stage B: 3 rows -> [krow][octet][x][16B] (conflict-free) ----
    {
        const int xs = t & 63;
        const int oct = t >> 6;             // wave-uniform octet base
        #pragma unroll
        for (int krow = 0; krow < 3; ++krow) {
            #pragma unroll
            for (int h = 0; h < 2; ++h) {
                const int o = oct + 8 * h;          // octet 0..15
                const int c0 = o * 8;
                const float* __restrict__ p =
                    imgb + (size_t)c0 * (RR * CCOLS) + (y + krow) * CCOLS + xs;
                unsigned v0, v1, v2, v3;
                v0 = (unsigned)f2bf(p[0])              | ((unsigned)f2bf(p[RR * CCOLS])     << 16);
                v1 = (unsigned)f2bf(p[2 * RR * CCOLS]) | ((unsigned)f2bf(p[3 * RR * CCOLS]) << 16);
                v2 = (unsigned)f2bf(p[4 * RR * CCOLS]) | ((unsigned)f2bf(p[5 * RR * CCOLS]) << 16);
                v3 = (unsigned)f2bf(p[6 * RR * CCOLS]) | ((unsigned)f2bf(p[7 * RR * CCOLS]) << 16);
                *(uint4*)(lds + krow * 16384 + o * 1024 + xs * 16) =
                    make_uint4(v0, v1, v2, v3);
            }
        }
    }

    // lane's coalesced A base (global) and B base (LDS byte address;
    // flat-low-32 == LDS offset, proven by R18's global_load_lds path)
    const unsigned char* __restrict__ pA = W9Tf + w * 1024 + l * 16;
    const unsigned bB = (unsigned)(uintptr_t)(lds + lhi * 1024 + lm * 16);

    __syncthreads();   // B staged; all counters drained

    // prologue: A chunks 0..3 and B chunk 0 in flight (opaque)
    bf16x8 aS0, aS1, aS2, aS3, b0c, b1c, b0n, b1n;
    asm volatile("global_load_dwordx4 %0, %1, off" : "=v"(aS0) : "v"(pA));
    asm volatile("global_load_dwordx4 %0, %1, off" : "=v"(aS1) : "v"(pA + CHUNK_STRIDE));
    asm volatile("global_load_dwordx4 %0, %1, off" : "=v"(aS2) : "v"(pA + 2 * CHUNK_STRIDE));
    asm volatile("global_load_dwordx4 %0, %1, off" : "=v"(aS3) : "v"(pA + 3 * CHUNK_STRIDE));
    asm volatile("ds_read_b128 %0, %1" : "=v"(b0c) : "v"(bB));
    asm volatile("ds_read_b128 %0, %1" : "=v"(b1c) : "v"(bB + 512u));

    f32x16 acc0 = {}, acc1 = {};

    // 72 straight-line K-steps; steady state vmcnt(3)/lgkmcnt(2)
    K4(0) K4(4) K4(8) K4(12) K4(16) K4(20) K4(24) K4(28) K4(32)
    K4(36) K4(40) K4(44) K4(48) K4(52) K4(56) K4(60) K4(64)
    KSTEP1(68, aS0, "3", "2") KSTEP1(69, aS1, "2", "2")
    KSTEP1(70, aS2, "1", "2") KSTEP1(71, aS3, "0", "0")

    // ---- epilogue: bias + store ----
    // C/D 32x32: col = lane&31, row = (reg&3) + 8*(reg>>2) + 4*(lane>>5)
    const int ocw = 32 * w;
    #pragma unroll
    for (int r = 0; r < 16; ++r) {
        const int oc = ocw + (r & 3) + 8 * (r >> 2) + 4 * lhi;
        const float bv = bias_dense[oc];
        const size_t ob = (((size_t)b * OC + oc) * HO + y) * WO;
        out[ob + lm] = acc0[r] + bv;             // x = lm < 62 always
        if (lm < 30)
            out[ob + 32 + lm] = acc1[r] + bv;    // x = 32+lm, clip at 62
    }
}

extern "C" void kernel_launch(void* const* d_in, const int* in_sizes, int n_in,
                              void* d_out, int out_size, void* d_ws, size_t ws_size,
                              hipStream_t stream) {
    const float* images             = (const float*)d_in[0];
    const float* weight_value       = (const float*)d_in[1];
    const int*   image_weight_index = (const int*)d_in[2];
    const int*   filter_lengths     = (const int*)d_in[3];
    const int*   start_points       = (const int*)d_in[4];
    const int*   bias_index         = (const int*)d_in[5];
    const float* bias_value         = (const float*)d_in[6];
    float* out = (float*)d_out;

    unsigned char* W9Tf = (unsigned char*)d_ws;
    float* bias_dense = (float*)((char*)d_ws + W9T_BYTES);

    hipMemsetAsync(d_ws, 0, W9T_BYTES, stream);
    prep_weights<<<OC + 1, 256, 0, stream>>>(weight_value, image_weight_index,
                                             filter_lengths, start_points, W9Tf,
                                             bias_index, bias_value, bias_dense,
                                             in_sizes[5]);

    dim3 grid(HO, NB);
    conv_mfma<<<grid, 512, 0, stream>>>(images, W9Tf, bias_dense, out);
}